// Round 1
// baseline (4095.218 us; speedup 1.0000x reference)
//
#include <hip/hip_runtime.h>
#include <math.h>

// Problem constants (match reference)
#define B_    2
#define T_    2048
#define C_    1024
#define HS_   8
#define DS_   32
#define HL_   8
#define DL_   128
#define HD_   64
#define WINS_ 256
#define WINL_ 1024

// ---------------------------------------------------------------------------
// Generic fp32 GEMM: C[M,N] = A[M,K] @ B[K,N], all row-major.
// 64x64 tile, 256 threads, 4x4 micro-tile per thread, K-tile 16.
// LDS padded to 68 floats/row: staging stores are <=2-way bank aliased (free).
// Requires M%64==0, N%64==0, K%16==0 (true for all 5 calls here).
// ---------------------------------------------------------------------------
__global__ __launch_bounds__(256) void sgemm64(const float* __restrict__ A,
                                               const float* __restrict__ Bm,
                                               float* __restrict__ Cm,
                                               int M, int N, int K) {
    __shared__ float As[16][68];   // [k][m]
    __shared__ float Bs[16][68];   // [k][n]
    const int tid = threadIdx.x;
    const int tileM = blockIdx.y * 64;
    const int tileN = blockIdx.x * 64;
    const int tx = tid & 15;    // 0..15 -> output cols tx*4..tx*4+3
    const int ty = tid >> 4;    // 0..15 -> output rows ty*4..ty*4+3

    // A-load mapping: thread -> (row am, k-offset ak), float4 along K
    const int am = tid >> 2;          // 0..63
    const int ak = (tid & 3) << 2;    // 0,4,8,12
    // B-load mapping: thread -> (k-row bk, col bn), float4 along N
    const int bk = tid >> 4;          // 0..15
    const int bn = (tid & 15) << 2;   // 0..60

    const float* Aptr = A + (size_t)(tileM + am) * K + ak;
    const float* Bptr = Bm + (size_t)bk * N + tileN + bn;

    float acc[4][4] = {};

    for (int kt = 0; kt < K; kt += 16) {
        float4 a4 = *(const float4*)(Aptr);
        float4 b4 = *(const float4*)(Bptr);
        Aptr += 16;
        Bptr += (size_t)16 * N;

        As[ak + 0][am] = a4.x;
        As[ak + 1][am] = a4.y;
        As[ak + 2][am] = a4.z;
        As[ak + 3][am] = a4.w;
        *(float4*)&Bs[bk][bn] = b4;
        __syncthreads();

#pragma unroll
        for (int k = 0; k < 16; ++k) {
            float4 av = *(const float4*)&As[k][ty * 4];
            float4 bv = *(const float4*)&Bs[k][tx * 4];
            acc[0][0] += av.x * bv.x; acc[0][1] += av.x * bv.y;
            acc[0][2] += av.x * bv.z; acc[0][3] += av.x * bv.w;
            acc[1][0] += av.y * bv.x; acc[1][1] += av.y * bv.y;
            acc[1][2] += av.y * bv.z; acc[1][3] += av.y * bv.w;
            acc[2][0] += av.z * bv.x; acc[2][1] += av.z * bv.y;
            acc[2][2] += av.z * bv.z; acc[2][3] += av.z * bv.w;
            acc[3][0] += av.w * bv.x; acc[3][1] += av.w * bv.y;
            acc[3][2] += av.w * bv.z; acc[3][3] += av.w * bv.w;
        }
        __syncthreads();
    }

#pragma unroll
    for (int i = 0; i < 4; ++i) {
        float4 o;
        o.x = acc[i][0]; o.y = acc[i][1]; o.z = acc[i][2]; o.w = acc[i][3];
        *(float4*)&Cm[(size_t)(tileM + ty * 4 + i) * N + tileN + tx * 4] = o;
    }
}

// ---------------------------------------------------------------------------
// Windowed causal attention, one query per block, 256 threads (4 waves).
// qk: [B*T, 2*H*DQK]  (q at col h*DQK, k at col H*DQK + h*DQK)
// v : [B*T, H*HD_]
// y : [B*T, C_], written at channel head_off + h*HD_ + d
// Wave w handles keys jj = w, w+4, ... ; dot via 64-lane butterfly reduce.
// ---------------------------------------------------------------------------
template <int DQK, int WIN>
__global__ __launch_bounds__(256) void attn_win(const float* __restrict__ qk,
                                                const float* __restrict__ v,
                                                float* __restrict__ y,
                                                int H, int head_off,
                                                float scale) {
    const int t = blockIdx.x;
    const int h = blockIdx.y;
    const int b = blockIdx.z;
    const int tid = threadIdx.x;
    const int lane = tid & 63;
    const int wv = tid >> 6;  // wave 0..3
    const int stride_qk = 2 * H * DQK;
    const int stride_v = H * HD_;

    __shared__ float q_s[DQK];
    __shared__ float p_s[WIN];
    __shared__ float red[4];
    __shared__ float outp[4][HD_];

    const float* qrow = qk + (size_t)(b * T_ + t) * stride_qk + h * DQK;
    for (int d = tid; d < DQK; d += 256) q_s[d] = qrow[d];
    __syncthreads();

    int j0 = t - WIN + 1;
    if (j0 < 0) j0 = 0;
    const int nk = t - j0 + 1;  // 1..WIN keys

    // ---- scores ----
    const float* kbase =
        qk + (size_t)(b * T_ + j0) * stride_qk + H * DQK + h * DQK;
    float wmax = -3.4e38f;
    for (int jj = wv; jj < nk; jj += 4) {
        const float* krow = kbase + (size_t)jj * stride_qk;
        float part = 0.f;
        for (int d = lane; d < DQK; d += 64) part += q_s[d] * krow[d];
#pragma unroll
        for (int off = 32; off > 0; off >>= 1)
            part += __shfl_xor(part, off, 64);
        part *= scale;
        if (lane == 0) p_s[jj] = part;
        wmax = fmaxf(wmax, part);  // uniform across lanes (butterfly)
    }
    if (lane == 0) red[wv] = wmax;
    __syncthreads();
    const float m = fmaxf(fmaxf(red[0], red[1]), fmaxf(red[2], red[3]));

    // ---- exp + sum ----
    float lsum = 0.f;
    for (int jj = tid; jj < nk; jj += 256) {
        float e = __expf(p_s[jj] - m);
        p_s[jj] = e;
        lsum += e;
    }
#pragma unroll
    for (int off = 32; off > 0; off >>= 1) lsum += __shfl_xor(lsum, off, 64);
    __syncthreads();  // red[] read above must complete before rewrite
    if (lane == 0) red[wv] = lsum;
    __syncthreads();
    const float denom = red[0] + red[1] + red[2] + red[3];

    // ---- P @ V ----  (lane owns output dim, wave owns key-stripe)
    const float* vbase = v + (size_t)(b * T_ + j0) * stride_v + h * HD_;
    float acc = 0.f;
    for (int jj = wv; jj < nk; jj += 4) {
        acc += p_s[jj] * vbase[(size_t)jj * stride_v + lane];
    }
    outp[wv][lane] = acc;
    __syncthreads();
    if (tid < HD_) {
        float o = (outp[0][tid] + outp[1][tid] + outp[2][tid] + outp[3][tid]) /
                  denom;
        y[(size_t)(b * T_ + t) * C_ + head_off + h * HD_ + tid] = o;
    }
}

// ---------------------------------------------------------------------------
extern "C" void kernel_launch(void* const* d_in, const int* in_sizes, int n_in,
                              void* d_out, int out_size, void* d_ws,
                              size_t ws_size, hipStream_t stream) {
    const float* x         = (const float*)d_in[0];  // [B,T,C]
    const float* Wqk_short = (const float*)d_in[1];  // [C, 512]
    const float* Wv_short  = (const float*)d_in[2];  // [C, 512]
    const float* Wqk_long  = (const float*)d_in[3];  // [C, 2048]
    const float* Wv_long   = (const float*)d_in[4];  // [C, 512]
    const float* Wproj     = (const float*)d_in[5];  // [C, C]
    float* out = (float*)d_out;                      // [B*T, C]

    const int M = B_ * T_;  // 4096

    // workspace layout (floats)
    float* ws = (float*)d_ws;
    float* qks = ws;                          // [M, 512]
    float* vs  = qks + (size_t)M * 512;       // [M, 512]
    float* qkl = vs + (size_t)M * 512;        // [M, 2048]
    float* vl  = qkl + (size_t)M * 2048;      // [M, 512]
    float* yb  = vl + (size_t)M * 512;        // [M, C]
    // total = 18,874,368 floats = 75.5 MB

    dim3 blk(256);
    // input projections
    sgemm64<<<dim3(512 / 64, M / 64), blk, 0, stream>>>(x, Wqk_short, qks, M, 512, C_);
    sgemm64<<<dim3(512 / 64, M / 64), blk, 0, stream>>>(x, Wv_short, vs, M, 512, C_);
    sgemm64<<<dim3(2048 / 64, M / 64), blk, 0, stream>>>(x, Wqk_long, qkl, M, 2048, C_);
    sgemm64<<<dim3(512 / 64, M / 64), blk, 0, stream>>>(x, Wv_long, vl, M, 512, C_);

    // attention (writes concatenated [B,T,C] activation)
    attn_win<DS_, WINS_><<<dim3(T_, HS_, B_), blk, 0, stream>>>(
        qks, vs, yb, HS_, 0, 0.17677669529663687f);            // 1/sqrt(32)
    attn_win<DL_, WINL_><<<dim3(T_, HL_, B_), blk, 0, stream>>>(
        qkl, vl, yb, HL_, HS_ * HD_, 0.08838834764831843f);    // 1/sqrt(128)

    // output projection
    sgemm64<<<dim3(C_ / 64, M / 64), blk, 0, stream>>>(yb, Wproj, out, M, C_, C_);
}

// Round 2
// 987.087 us; speedup vs baseline: 4.1488x; 4.1488x over previous
//
#include <hip/hip_runtime.h>
#include <math.h>

// Problem constants (match reference)
#define B_    2
#define T_    2048
#define C_    1024
#define HS_   8
#define DS_   32
#define HL_   8
#define DL_   128
#define HD_   64
#define WINS_ 256
#define WINL_ 1024

// ---------------------------------------------------------------------------
// Generic fp32 GEMM: C[M,N] = A[M,K] @ B[K,N], all row-major. (unchanged, R0)
// ---------------------------------------------------------------------------
__global__ __launch_bounds__(256) void sgemm64(const float* __restrict__ A,
                                               const float* __restrict__ Bm,
                                               float* __restrict__ Cm,
                                               int M, int N, int K) {
    __shared__ float As[16][68];   // [k][m]
    __shared__ float Bs[16][68];   // [k][n]
    const int tid = threadIdx.x;
    const int tileM = blockIdx.y * 64;
    const int tileN = blockIdx.x * 64;
    const int tx = tid & 15;
    const int ty = tid >> 4;

    const int am = tid >> 2;
    const int ak = (tid & 3) << 2;
    const int bk = tid >> 4;
    const int bn = (tid & 15) << 2;

    const float* Aptr = A + (size_t)(tileM + am) * K + ak;
    const float* Bptr = Bm + (size_t)bk * N + tileN + bn;

    float acc[4][4] = {};

    for (int kt = 0; kt < K; kt += 16) {
        float4 a4 = *(const float4*)(Aptr);
        float4 b4 = *(const float4*)(Bptr);
        Aptr += 16;
        Bptr += (size_t)16 * N;

        As[ak + 0][am] = a4.x;
        As[ak + 1][am] = a4.y;
        As[ak + 2][am] = a4.z;
        As[ak + 3][am] = a4.w;
        *(float4*)&Bs[bk][bn] = b4;
        __syncthreads();

#pragma unroll
        for (int k = 0; k < 16; ++k) {
            float4 av = *(const float4*)&As[k][ty * 4];
            float4 bv = *(const float4*)&Bs[k][tx * 4];
            acc[0][0] += av.x * bv.x; acc[0][1] += av.x * bv.y;
            acc[0][2] += av.x * bv.z; acc[0][3] += av.x * bv.w;
            acc[1][0] += av.y * bv.x; acc[1][1] += av.y * bv.y;
            acc[1][2] += av.y * bv.z; acc[1][3] += av.y * bv.w;
            acc[2][0] += av.z * bv.x; acc[2][1] += av.z * bv.y;
            acc[2][2] += av.z * bv.z; acc[2][3] += av.z * bv.w;
            acc[3][0] += av.w * bv.x; acc[3][1] += av.w * bv.y;
            acc[3][2] += av.w * bv.z; acc[3][3] += av.w * bv.w;
        }
        __syncthreads();
    }

#pragma unroll
    for (int i = 0; i < 4; ++i) {
        float4 o;
        o.x = acc[i][0]; o.y = acc[i][1]; o.z = acc[i][2]; o.w = acc[i][3];
        *(float4*)&Cm[(size_t)(tileM + ty * 4 + i) * N + tileN + tx * 4] = o;
    }
}

// ---------------------------------------------------------------------------
// Flash-style windowed causal attention.
// Block: 256 threads, one 64-query tile for one (b,h). K-tiles of 64 keys.
// Score GEMM: S[64q][64k] from transposed LDS tiles Qs[d][q], KP[d][k]
//   (D>64 handled in two 64-d passes, re-staging KP).
// Online softmax: per-row m,l replicated across the 16-lane row group.
// PV GEMM: P (written into dead KP region, natural [q][k]) x Vs[k][d].
// LDS: Qs D*64 | KP max(64*64, Ps 64*64) | Vs 64*64  (long: exactly 64 KB)
// ---------------------------------------------------------------------------
template <int D, int WIN>
__global__ __launch_bounds__(256, 2) void attn_flash(
    const float* __restrict__ qk, const float* __restrict__ vv,
    float* __restrict__ y, float scale, int head_off) {
    constexpr int H = 8;
    constexpr int DH = (D > 64) ? 64 : D;      // d-chunk per score pass
    constexpr int NPASS = D / DH;
    constexpr int SQK = 2 * H * D;             // qk row stride (floats)
    constexpr int SV = H * HD_;                // v row stride
    constexpr int KP_SZ = (DH * 64 > 4096) ? DH * 64 : 4096;

    __shared__ float Qs[D * 64];   // transposed: Qs[d*64 + qrow]
    __shared__ float KP[KP_SZ];    // K-half transposed [d][k]  (later: Ps[q][k])
    __shared__ float Vs[64 * 64];  // natural [k][d]

    const int t0 = blockIdx.x * 64;
    const int h = blockIdx.y;
    const int b = blockIdx.z;
    const int tid = threadIdx.x;
    const int tx = tid & 15;
    const int ty = tid >> 4;
    const int ty4 = ty * 4;
    const int tx4 = tx * 4;

    const float* qbase = qk + (size_t)(b * T_ + t0) * SQK + h * D;
    const float* kbase = qk + (size_t)b * T_ * SQK + H * D + h * D;
    const float* vbase = vv + (size_t)b * T_ * SV + h * HD_;

    // ---- stage Q transposed (pre-scaled) ----
    // idx bits: c4(2) | rowlow(4) | rowhigh(2) | seg(rest)
    for (int idx = tid; idx < 64 * (D / 4); idx += 256) {
        const int c4 = idx & 3;
        const int row = ((idx >> 2) & 15) | (((idx >> 6) & 3) << 4);
        const int seg = idx >> 8;
        const int d = seg * 16 + c4 * 4;
        const float4 q4 = *(const float4*)(qbase + (size_t)row * SQK + d);
        Qs[(d + 0) * 64 + row] = q4.x * scale;
        Qs[(d + 1) * 64 + row] = q4.y * scale;
        Qs[(d + 2) * 64 + row] = q4.z * scale;
        Qs[(d + 3) * 64 + row] = q4.w * scale;
    }

    float o[4][4] = {};
    float m_i[4], l_i[4];
#pragma unroll
    for (int i = 0; i < 4; ++i) { m_i[i] = -1e30f; l_i[i] = 0.f; }

    int k0s = t0 - WIN + 1;
    if (k0s < 0) k0s = 0;
    k0s &= ~63;

    for (int k0 = k0s; k0 <= t0; k0 += 64) {
        float s[4][4] = {};
        for (int p = 0; p < NPASS; ++p) {
            __syncthreads();  // KP/Vs free (prev phase's readers done)
            // stage K d-half, transposed
            for (int idx = tid; idx < 64 * (DH / 4); idx += 256) {
                const int c4 = idx & 3;
                const int row = ((idx >> 2) & 15) | (((idx >> 6) & 3) << 4);
                const int seg = idx >> 8;
                const int d = seg * 16 + c4 * 4;
                const float4 k4 =
                    *(const float4*)(kbase + (size_t)(k0 + row) * SQK + p * DH + d);
                KP[(d + 0) * 64 + row] = k4.x;
                KP[(d + 1) * 64 + row] = k4.y;
                KP[(d + 2) * 64 + row] = k4.z;
                KP[(d + 3) * 64 + row] = k4.w;
            }
            if (p == 0) {  // stage V (natural layout, coalesced both sides)
                for (int idx = tid; idx < 64 * 16; idx += 256) {
                    const int dq = idx & 15;
                    const int row = idx >> 4;
                    *(float4*)&Vs[row * 64 + dq * 4] =
                        *(const float4*)(vbase + (size_t)(k0 + row) * SV + dq * 4);
                }
            }
            __syncthreads();
            const float* Qp = Qs + p * (DH * 64);
#pragma unroll 8
            for (int d = 0; d < DH; ++d) {
                const float4 q4 = *(const float4*)&Qp[d * 64 + ty4];
                const float4 k4 = *(const float4*)&KP[d * 64 + tx4];
                s[0][0] += q4.x * k4.x; s[0][1] += q4.x * k4.y;
                s[0][2] += q4.x * k4.z; s[0][3] += q4.x * k4.w;
                s[1][0] += q4.y * k4.x; s[1][1] += q4.y * k4.y;
                s[1][2] += q4.y * k4.z; s[1][3] += q4.y * k4.w;
                s[2][0] += q4.z * k4.x; s[2][1] += q4.z * k4.y;
                s[2][2] += q4.z * k4.z; s[2][3] += q4.z * k4.w;
                s[3][0] += q4.w * k4.x; s[3][1] += q4.w * k4.y;
                s[3][2] += q4.w * k4.z; s[3][3] += q4.w * k4.w;
            }
        }

        // ---- mask (edge tiles only; finite NEG self-corrects via rescale) ----
        const bool full = (k0 >= t0 + 64 - WIN) && (k0 + 64 <= t0);
        if (!full) {
#pragma unroll
            for (int i = 0; i < 4; ++i) {
                const int qi = t0 + ty4 + i;
#pragma unroll
                for (int j = 0; j < 4; ++j) {
                    const int kj = k0 + tx4 + j;
                    const int rel = qi - kj;
                    if (rel < 0 || rel >= WIN) s[i][j] = -1e30f;
                }
            }
        }

        // ---- online softmax (row state replicated over 16-lane row group) ----
#pragma unroll
        for (int i = 0; i < 4; ++i) {
            float rm = fmaxf(fmaxf(s[i][0], s[i][1]), fmaxf(s[i][2], s[i][3]));
            rm = fmaxf(rm, __shfl_xor(rm, 1, 64));
            rm = fmaxf(rm, __shfl_xor(rm, 2, 64));
            rm = fmaxf(rm, __shfl_xor(rm, 4, 64));
            rm = fmaxf(rm, __shfl_xor(rm, 8, 64));
            const float mn = fmaxf(m_i[i], rm);
            const float a = __expf(m_i[i] - mn);
            m_i[i] = mn;
            float sum = 0.f;
#pragma unroll
            for (int j = 0; j < 4; ++j) {
                const float e = __expf(s[i][j] - mn);
                s[i][j] = e;
                sum += e;
            }
            sum += __shfl_xor(sum, 1, 64);
            sum += __shfl_xor(sum, 2, 64);
            sum += __shfl_xor(sum, 4, 64);
            sum += __shfl_xor(sum, 8, 64);
            l_i[i] = l_i[i] * a + sum;
            o[i][0] *= a; o[i][1] *= a; o[i][2] *= a; o[i][3] *= a;
        }

        __syncthreads();  // all waves done reading KP as K
        // write P into dead KP region, natural [q][k]
#pragma unroll
        for (int i = 0; i < 4; ++i) {
            float4 pr;
            pr.x = s[i][0]; pr.y = s[i][1]; pr.z = s[i][2]; pr.w = s[i][3];
            *(float4*)&KP[(ty4 + i) * 64 + tx4] = pr;
        }
        __syncthreads();  // P visible

        // ---- PV GEMM: o[i][j] += sum_k P[q][k] * V[k][d] ----
#pragma unroll 8
        for (int k4 = 0; k4 < 64; k4 += 4) {
            const float4 p0 = *(const float4*)&KP[(ty4 + 0) * 64 + k4];
            const float4 p1 = *(const float4*)&KP[(ty4 + 1) * 64 + k4];
            const float4 p2 = *(const float4*)&KP[(ty4 + 2) * 64 + k4];
            const float4 p3 = *(const float4*)&KP[(ty4 + 3) * 64 + k4];
            const float4 v0 = *(const float4*)&Vs[(k4 + 0) * 64 + tx4];
            const float4 v1 = *(const float4*)&Vs[(k4 + 1) * 64 + tx4];
            const float4 v2 = *(const float4*)&Vs[(k4 + 2) * 64 + tx4];
            const float4 v3 = *(const float4*)&Vs[(k4 + 3) * 64 + tx4];
            o[0][0] += p0.x * v0.x + p0.y * v1.x + p0.z * v2.x + p0.w * v3.x;
            o[0][1] += p0.x * v0.y + p0.y * v1.y + p0.z * v2.y + p0.w * v3.y;
            o[0][2] += p0.x * v0.z + p0.y * v1.z + p0.z * v2.z + p0.w * v3.z;
            o[0][3] += p0.x * v0.w + p0.y * v1.w + p0.z * v2.w + p0.w * v3.w;
            o[1][0] += p1.x * v0.x + p1.y * v1.x + p1.z * v2.x + p1.w * v3.x;
            o[1][1] += p1.x * v0.y + p1.y * v1.y + p1.z * v2.y + p1.w * v3.y;
            o[1][2] += p1.x * v0.z + p1.y * v1.z + p1.z * v2.z + p1.w * v3.z;
            o[1][3] += p1.x * v0.w + p1.y * v1.w + p1.z * v2.w + p1.w * v3.w;
            o[2][0] += p2.x * v0.x + p2.y * v1.x + p2.z * v2.x + p2.w * v3.x;
            o[2][1] += p2.x * v0.y + p2.y * v1.y + p2.z * v2.y + p2.w * v3.y;
            o[2][2] += p2.x * v0.z + p2.y * v1.z + p2.z * v2.z + p2.w * v3.z;
            o[2][3] += p2.x * v0.w + p2.y * v1.w + p2.z * v2.w + p2.w * v3.w;
            o[3][0] += p3.x * v0.x + p3.y * v1.x + p3.z * v2.x + p3.w * v3.x;
            o[3][1] += p3.x * v0.y + p3.y * v1.y + p3.z * v2.y + p3.w * v3.y;
            o[3][2] += p3.x * v0.z + p3.y * v1.z + p3.z * v2.z + p3.w * v3.z;
            o[3][3] += p3.x * v0.w + p3.y * v1.w + p3.z * v2.w + p3.w * v3.w;
        }
    }

    // ---- epilogue: normalize and write into concatenated [B,T,C] ----
    float* yrow = y + (size_t)(b * T_ + t0) * C_ + head_off + h * HD_;
#pragma unroll
    for (int i = 0; i < 4; ++i) {
        const float inv = 1.f / l_i[i];
        float4 r;
        r.x = o[i][0] * inv; r.y = o[i][1] * inv;
        r.z = o[i][2] * inv; r.w = o[i][3] * inv;
        *(float4*)(yrow + (size_t)(ty4 + i) * C_ + tx4) = r;
    }
}

// ---------------------------------------------------------------------------
extern "C" void kernel_launch(void* const* d_in, const int* in_sizes, int n_in,
                              void* d_out, int out_size, void* d_ws,
                              size_t ws_size, hipStream_t stream) {
    const float* x         = (const float*)d_in[0];
    const float* Wqk_short = (const float*)d_in[1];
    const float* Wv_short  = (const float*)d_in[2];
    const float* Wqk_long  = (const float*)d_in[3];
    const float* Wv_long   = (const float*)d_in[4];
    const float* Wproj     = (const float*)d_in[5];
    float* out = (float*)d_out;

    const int M = B_ * T_;  // 4096

    float* ws = (float*)d_ws;
    float* qks = ws;                          // [M, 512]
    float* vs  = qks + (size_t)M * 512;       // [M, 512]
    float* qkl = vs + (size_t)M * 512;        // [M, 2048]
    float* vl  = qkl + (size_t)M * 2048;      // [M, 512]
    float* yb  = vl + (size_t)M * 512;        // [M, C]

    dim3 blk(256);
    sgemm64<<<dim3(512 / 64, M / 64), blk, 0, stream>>>(x, Wqk_short, qks, M, 512, C_);
    sgemm64<<<dim3(512 / 64, M / 64), blk, 0, stream>>>(x, Wv_short, vs, M, 512, C_);
    sgemm64<<<dim3(2048 / 64, M / 64), blk, 0, stream>>>(x, Wqk_long, qkl, M, 2048, C_);
    sgemm64<<<dim3(512 / 64, M / 64), blk, 0, stream>>>(x, Wv_long, vl, M, 512, C_);

    attn_flash<DS_, WINS_><<<dim3(T_ / 64, HS_, B_), blk, 0, stream>>>(
        qks, vs, yb, 0.17677669529663687f, 0);
    attn_flash<DL_, WINL_><<<dim3(T_ / 64, HL_, B_), blk, 0, stream>>>(
        qkl, vl, yb, 0.08838834764831843f, HS_ * HD_);

    sgemm64<<<dim3(C_ / 64, M / 64), blk, 0, stream>>>(yb, Wproj, out, M, C_, C_);
}

// Round 3
// 468.839 us; speedup vs baseline: 8.7348x; 2.1054x over previous
//
#include <hip/hip_runtime.h>
#include <math.h>

// Problem constants (match reference)
#define B_    2
#define T_    2048
#define C_    1024
#define HS_   8
#define DS_   32
#define HL_   8
#define DL_   128
#define HD_   64
#define WINS_ 256
#define WINL_ 1024
#define NALL_ 3584   // 512 (qk_s) + 512 (v_s) + 2048 (qk_l) + 512 (v_l)

typedef __bf16 bf16x8 __attribute__((ext_vector_type(8)));
typedef float floatx4 __attribute__((ext_vector_type(4)));

__device__ __forceinline__ ushort f2bf(float f) {
    union { float f; unsigned u; } v; v.f = f;
    unsigned r = v.u + 0x7fff + ((v.u >> 16) & 1);  // RNE
    return (ushort)(r >> 16);
}

// ---------------------------------------------------------------------------
// x (fp32) -> bf16, vectorized
// ---------------------------------------------------------------------------
__global__ __launch_bounds__(256) void cvt_bf16(const float* __restrict__ in,
                                                ushort* __restrict__ out, int n4) {
    int i = blockIdx.x * 256 + threadIdx.x;
    if (i >= n4) return;
    float4 v = ((const float4*)in)[i];
    ushort4 o;
    o.x = f2bf(v.x); o.y = f2bf(v.y); o.z = f2bf(v.z); o.w = f2bf(v.w);
    ((ushort4*)out)[i] = o;
}

// ---------------------------------------------------------------------------
// W [K=1024][N] fp32 -> WT bf16 rows [rowoff, rowoff+N) of [*][1024]
// 32x32 LDS tile transpose, 256 threads.
// ---------------------------------------------------------------------------
__global__ __launch_bounds__(256) void transpose_cvt(const float* __restrict__ W,
                                                     ushort* __restrict__ WT,
                                                     int N, int rowoff) {
    __shared__ float t[32][33];
    const int n0 = blockIdx.x * 32;
    const int k0 = blockIdx.y * 32;
    const int tx = threadIdx.x & 31;
    const int ty = threadIdx.x >> 5;  // 0..7
#pragma unroll
    for (int i = 0; i < 4; ++i)
        t[ty + 8 * i][tx] = W[(size_t)(k0 + ty + 8 * i) * N + n0 + tx];
    __syncthreads();
#pragma unroll
    for (int i = 0; i < 4; ++i)
        WT[(size_t)(rowoff + n0 + ty + 8 * i) * 1024 + k0 + tx] =
            f2bf(t[tx][ty + 8 * i]);
}

// ---------------------------------------------------------------------------
// bf16 MFMA GEMM: C[M,N] fp32 = A[M,K] bf16 @ BT[N,K] bf16 (B^T layout).
// 128x128 tile / 256 threads (4 waves, 2x2 of 64x64), BK=32, 16x16x32 MFMA.
// A-frag: A[m=lane&15][k=quad*8+j]; B-frag: BT[n=lane&15][k=quad*8+j];
// C/D: col=lane&15, row=quad*4+reg  [learn_hip m89/m91 verified layouts]
// ---------------------------------------------------------------------------
__global__ __launch_bounds__(256) void gemm_bf16(const ushort* __restrict__ A,
                                                 const ushort* __restrict__ BT,
                                                 float* __restrict__ Cm,
                                                 int M, int N, int K) {
    __shared__ ushort As[128 * 32];
    __shared__ ushort Bs[128 * 32];
    const int tid = threadIdx.x;
    const int m0 = blockIdx.y * 128;
    const int n0 = blockIdx.x * 128;
    const int wave = tid >> 6;
    const int lane = tid & 63;
    const int wm = (wave >> 1) * 64;
    const int wn = (wave & 1) * 64;
    const int l15 = lane & 15;
    const int quad = lane >> 4;

    // staging: thread -> (row=tid>>2 [+64], 16B chunk (tid&3))
    const int srow = tid >> 2;
    const int sc = (tid & 3) * 8;

    floatx4 acc[4][4] = {};

    const ushort* Ap0 = A + (size_t)(m0 + srow) * K + sc;
    const ushort* Ap1 = A + (size_t)(m0 + srow + 64) * K + sc;
    const ushort* Bp0 = BT + (size_t)(n0 + srow) * K + sc;
    const ushort* Bp1 = BT + (size_t)(n0 + srow + 64) * K + sc;

    for (int kt = 0; kt < K; kt += 32) {
        const int4 a0 = *(const int4*)(Ap0 + kt);
        const int4 a1 = *(const int4*)(Ap1 + kt);
        const int4 b0 = *(const int4*)(Bp0 + kt);
        const int4 b1 = *(const int4*)(Bp1 + kt);
        __syncthreads();  // prev iter's frag reads done
        *(int4*)&As[srow * 32 + sc] = a0;
        *(int4*)&As[(srow + 64) * 32 + sc] = a1;
        *(int4*)&Bs[srow * 32 + sc] = b0;
        *(int4*)&Bs[(srow + 64) * 32 + sc] = b1;
        __syncthreads();

        bf16x8 af[4], bfr[4];
#pragma unroll
        for (int i = 0; i < 4; ++i)
            af[i] = *(const bf16x8*)&As[(wm + i * 16 + l15) * 32 + quad * 8];
#pragma unroll
        for (int j = 0; j < 4; ++j)
            bfr[j] = *(const bf16x8*)&Bs[(wn + j * 16 + l15) * 32 + quad * 8];
#pragma unroll
        for (int i = 0; i < 4; ++i)
#pragma unroll
            for (int j = 0; j < 4; ++j)
                acc[i][j] = __builtin_amdgcn_mfma_f32_16x16x32_bf16(
                    af[i], bfr[j], acc[i][j], 0, 0, 0);
    }

#pragma unroll
    for (int i = 0; i < 4; ++i)
#pragma unroll
        for (int j = 0; j < 4; ++j)
#pragma unroll
            for (int r = 0; r < 4; ++r)
                Cm[(size_t)(m0 + wm + i * 16 + quad * 4 + r) * N + n0 + wn +
                   j * 16 + l15] = acc[i][j][r];
}

// ---------------------------------------------------------------------------
// Flash-style windowed causal attention (R1 structure; reads strided act,
// writes bf16 output for the proj GEMM).
// ---------------------------------------------------------------------------
template <int D, int WIN>
__global__ __launch_bounds__(256, 2) void attn_flash(
    const float* __restrict__ act, ushort* __restrict__ y, float scale,
    int qoff, int koff, int voff, int stride, int head_off) {
    constexpr int DH = (D > 64) ? 64 : D;
    constexpr int NPASS = D / DH;
    constexpr int KP_SZ = (DH * 64 > 4096) ? DH * 64 : 4096;

    __shared__ float Qs[D * 64];
    __shared__ float KP[KP_SZ];
    __shared__ float Vs[64 * 64];

    const int t0 = blockIdx.x * 64;
    const int h = blockIdx.y;
    const int b = blockIdx.z;
    const int tid = threadIdx.x;
    const int tx = tid & 15;
    const int ty = tid >> 4;
    const int ty4 = ty * 4;
    const int tx4 = tx * 4;

    const float* qbase = act + (size_t)(b * T_ + t0) * stride + qoff + h * D;
    const float* kbase = act + (size_t)(b * T_) * stride + koff + h * D;
    const float* vbase = act + (size_t)(b * T_) * stride + voff + h * HD_;

    for (int idx = tid; idx < 64 * (D / 4); idx += 256) {
        const int c4 = idx & 3;
        const int row = ((idx >> 2) & 15) | (((idx >> 6) & 3) << 4);
        const int seg = idx >> 8;
        const int d = seg * 16 + c4 * 4;
        const float4 q4 = *(const float4*)(qbase + (size_t)row * stride + d);
        Qs[(d + 0) * 64 + row] = q4.x * scale;
        Qs[(d + 1) * 64 + row] = q4.y * scale;
        Qs[(d + 2) * 64 + row] = q4.z * scale;
        Qs[(d + 3) * 64 + row] = q4.w * scale;
    }

    float o[4][4] = {};
    float m_i[4], l_i[4];
#pragma unroll
    for (int i = 0; i < 4; ++i) { m_i[i] = -1e30f; l_i[i] = 0.f; }

    int k0s = t0 - WIN + 1;
    if (k0s < 0) k0s = 0;
    k0s &= ~63;

    for (int k0 = k0s; k0 <= t0; k0 += 64) {
        float s[4][4] = {};
        for (int p = 0; p < NPASS; ++p) {
            __syncthreads();
            for (int idx = tid; idx < 64 * (DH / 4); idx += 256) {
                const int c4 = idx & 3;
                const int row = ((idx >> 2) & 15) | (((idx >> 6) & 3) << 4);
                const int seg = idx >> 8;
                const int d = seg * 16 + c4 * 4;
                const float4 k4 = *(const float4*)(
                    kbase + (size_t)(k0 + row) * stride + p * DH + d);
                KP[(d + 0) * 64 + row] = k4.x;
                KP[(d + 1) * 64 + row] = k4.y;
                KP[(d + 2) * 64 + row] = k4.z;
                KP[(d + 3) * 64 + row] = k4.w;
            }
            if (p == 0) {
                for (int idx = tid; idx < 64 * 16; idx += 256) {
                    const int dq = idx & 15;
                    const int row = idx >> 4;
                    *(float4*)&Vs[row * 64 + dq * 4] = *(const float4*)(
                        vbase + (size_t)(k0 + row) * stride + dq * 4);
                }
            }
            __syncthreads();
            const float* Qp = Qs + p * (DH * 64);
#pragma unroll 8
            for (int d = 0; d < DH; ++d) {
                const float4 q4 = *(const float4*)&Qp[d * 64 + ty4];
                const float4 k4 = *(const float4*)&KP[d * 64 + tx4];
                s[0][0] += q4.x * k4.x; s[0][1] += q4.x * k4.y;
                s[0][2] += q4.x * k4.z; s[0][3] += q4.x * k4.w;
                s[1][0] += q4.y * k4.x; s[1][1] += q4.y * k4.y;
                s[1][2] += q4.y * k4.z; s[1][3] += q4.y * k4.w;
                s[2][0] += q4.z * k4.x; s[2][1] += q4.z * k4.y;
                s[2][2] += q4.z * k4.z; s[2][3] += q4.z * k4.w;
                s[3][0] += q4.w * k4.x; s[3][1] += q4.w * k4.y;
                s[3][2] += q4.w * k4.z; s[3][3] += q4.w * k4.w;
            }
        }

        const bool full = (k0 >= t0 + 64 - WIN) && (k0 + 64 <= t0);
        if (!full) {
#pragma unroll
            for (int i = 0; i < 4; ++i) {
                const int qi = t0 + ty4 + i;
#pragma unroll
                for (int j = 0; j < 4; ++j) {
                    const int kj = k0 + tx4 + j;
                    const int rel = qi - kj;
                    if (rel < 0 || rel >= WIN) s[i][j] = -1e30f;
                }
            }
        }

#pragma unroll
        for (int i = 0; i < 4; ++i) {
            float rm = fmaxf(fmaxf(s[i][0], s[i][1]), fmaxf(s[i][2], s[i][3]));
            rm = fmaxf(rm, __shfl_xor(rm, 1, 64));
            rm = fmaxf(rm, __shfl_xor(rm, 2, 64));
            rm = fmaxf(rm, __shfl_xor(rm, 4, 64));
            rm = fmaxf(rm, __shfl_xor(rm, 8, 64));
            const float mn = fmaxf(m_i[i], rm);
            const float a = __expf(m_i[i] - mn);
            m_i[i] = mn;
            float sum = 0.f;
#pragma unroll
            for (int j = 0; j < 4; ++j) {
                const float e = __expf(s[i][j] - mn);
                s[i][j] = e;
                sum += e;
            }
            sum += __shfl_xor(sum, 1, 64);
            sum += __shfl_xor(sum, 2, 64);
            sum += __shfl_xor(sum, 4, 64);
            sum += __shfl_xor(sum, 8, 64);
            l_i[i] = l_i[i] * a + sum;
            o[i][0] *= a; o[i][1] *= a; o[i][2] *= a; o[i][3] *= a;
        }

        __syncthreads();
#pragma unroll
        for (int i = 0; i < 4; ++i) {
            float4 pr;
            pr.x = s[i][0]; pr.y = s[i][1]; pr.z = s[i][2]; pr.w = s[i][3];
            *(float4*)&KP[(ty4 + i) * 64 + tx4] = pr;
        }
        __syncthreads();

#pragma unroll 8
        for (int k4 = 0; k4 < 64; k4 += 4) {
            const float4 p0 = *(const float4*)&KP[(ty4 + 0) * 64 + k4];
            const float4 p1 = *(const float4*)&KP[(ty4 + 1) * 64 + k4];
            const float4 p2 = *(const float4*)&KP[(ty4 + 2) * 64 + k4];
            const float4 p3 = *(const float4*)&KP[(ty4 + 3) * 64 + k4];
            const float4 v0 = *(const float4*)&Vs[(k4 + 0) * 64 + tx4];
            const float4 v1 = *(const float4*)&Vs[(k4 + 1) * 64 + tx4];
            const float4 v2 = *(const float4*)&Vs[(k4 + 2) * 64 + tx4];
            const float4 v3 = *(const float4*)&Vs[(k4 + 3) * 64 + tx4];
            o[0][0] += p0.x * v0.x + p0.y * v1.x + p0.z * v2.x + p0.w * v3.x;
            o[0][1] += p0.x * v0.y + p0.y * v1.y + p0.z * v2.y + p0.w * v3.y;
            o[0][2] += p0.x * v0.z + p0.y * v1.z + p0.z * v2.z + p0.w * v3.z;
            o[0][3] += p0.x * v0.w + p0.y * v1.w + p0.z * v2.w + p0.w * v3.w;
            o[1][0] += p1.x * v0.x + p1.y * v1.x + p1.z * v2.x + p1.w * v3.x;
            o[1][1] += p1.x * v0.y + p1.y * v1.y + p1.z * v2.y + p1.w * v3.y;
            o[1][2] += p1.x * v0.z + p1.y * v1.z + p1.z * v2.z + p1.w * v3.z;
            o[1][3] += p1.x * v0.w + p1.y * v1.w + p1.z * v2.w + p1.w * v3.w;
            o[2][0] += p2.x * v0.x + p2.y * v1.x + p2.z * v2.x + p2.w * v3.x;
            o[2][1] += p2.x * v0.y + p2.y * v1.y + p2.z * v2.y + p2.w * v3.y;
            o[2][2] += p2.x * v0.z + p2.y * v1.z + p2.z * v2.z + p2.w * v3.z;
            o[2][3] += p2.x * v0.w + p2.y * v1.w + p2.z * v2.w + p2.w * v3.w;
            o[3][0] += p3.x * v0.x + p3.y * v1.x + p3.z * v2.x + p3.w * v3.x;
            o[3][1] += p3.x * v0.y + p3.y * v1.y + p3.z * v2.y + p3.w * v3.y;
            o[3][2] += p3.x * v0.z + p3.y * v1.z + p3.z * v2.z + p3.w * v3.z;
            o[3][3] += p3.x * v0.w + p3.y * v1.w + p3.z * v2.w + p3.w * v3.w;
        }
    }

    ushort* yrow = y + (size_t)(b * T_ + t0) * C_ + head_off + h * HD_;
#pragma unroll
    for (int i = 0; i < 4; ++i) {
        const float inv = 1.f / l_i[i];
        ushort4 r;
        r.x = f2bf(o[i][0] * inv);
        r.y = f2bf(o[i][1] * inv);
        r.z = f2bf(o[i][2] * inv);
        r.w = f2bf(o[i][3] * inv);
        *(ushort4*)(yrow + (size_t)(ty4 + i) * C_ + tx4) = r;
    }
}

// ---------------------------------------------------------------------------
extern "C" void kernel_launch(void* const* d_in, const int* in_sizes, int n_in,
                              void* d_out, int out_size, void* d_ws,
                              size_t ws_size, hipStream_t stream) {
    const float* x         = (const float*)d_in[0];
    const float* Wqk_short = (const float*)d_in[1];
    const float* Wv_short  = (const float*)d_in[2];
    const float* Wqk_long  = (const float*)d_in[3];
    const float* Wv_long   = (const float*)d_in[4];
    const float* Wproj     = (const float*)d_in[5];
    float* out = (float*)d_out;

    const int M = B_ * T_;  // 4096

    // workspace layout
    ushort* x16    = (ushort*)d_ws;                    // [4096][1024] bf16
    ushort* WallT  = x16 + (size_t)M * C_;             // [3584][1024] bf16
    ushort* WprojT = WallT + (size_t)NALL_ * C_;       // [1024][1024] bf16
    ushort* yb16   = WprojT + (size_t)C_ * C_;         // [4096][1024] bf16
    float*  act    = (float*)(yb16 + (size_t)M * C_);  // [4096][3584] fp32
    // total ~85 MB

    dim3 blk(256);
    // conversions (independent)
    cvt_bf16<<<dim3(M * C_ / 4 / 256), blk, 0, stream>>>(x, x16, M * C_ / 4);
    transpose_cvt<<<dim3(512 / 32, 32), blk, 0, stream>>>(Wqk_short, WallT, 512, 0);
    transpose_cvt<<<dim3(512 / 32, 32), blk, 0, stream>>>(Wv_short, WallT, 512, 512);
    transpose_cvt<<<dim3(2048 / 32, 32), blk, 0, stream>>>(Wqk_long, WallT, 2048, 1024);
    transpose_cvt<<<dim3(512 / 32, 32), blk, 0, stream>>>(Wv_long, WallT, 512, 3072);
    transpose_cvt<<<dim3(1024 / 32, 32), blk, 0, stream>>>(Wproj, WprojT, 1024, 0);

    // fused input projections: act = x16 @ WallT^T  -> [4096][3584]
    gemm_bf16<<<dim3(NALL_ / 128, M / 128), blk, 0, stream>>>(x16, WallT, act,
                                                              M, NALL_, C_);

    // attention: col layout of act = [qs 0..512 | vs 512..1024 | ql 1024..3072 | vl 3072..3584]
    attn_flash<DS_, WINS_><<<dim3(T_ / 64, HS_, B_), blk, 0, stream>>>(
        act, yb16, 0.17677669529663687f, 0, 256, 512, NALL_, 0);
    attn_flash<DL_, WINL_><<<dim3(T_ / 64, HL_, B_), blk, 0, stream>>>(
        act, yb16, 0.08838834764831843f, 1024, 2048, 3072, NALL_, HS_ * HD_);

    // output projection
    gemm_bf16<<<dim3(C_ / 128, M / 128), blk, 0, stream>>>(yb16, WprojT, out,
                                                           M, C_, C_);
}

// Round 4
// 259.007 us; speedup vs baseline: 15.8112x; 1.8101x over previous
//
#include <hip/hip_runtime.h>
#include <math.h>

// Problem constants (match reference)
#define B_    2
#define T_    2048
#define C_    1024
#define HS_   8
#define DS_   32
#define HL_   8
#define DL_   128
#define HD_   64
#define WINS_ 256
#define WINL_ 1024
#define NALL_ 3584   // 512 (qk_s) + 512 (v_s) + 2048 (qk_l) + 512 (v_l)

typedef __bf16 bf16x8 __attribute__((ext_vector_type(8)));
typedef float floatx4 __attribute__((ext_vector_type(4)));

__device__ __forceinline__ ushort f2bf(float f) {
    union { float f; unsigned u; } v; v.f = f;
    unsigned r = v.u + 0x7fff + ((v.u >> 16) & 1);  // RNE
    return (ushort)(r >> 16);
}

// ---------------------------------------------------------------------------
// x (fp32) -> bf16, vectorized
// ---------------------------------------------------------------------------
__global__ __launch_bounds__(256) void cvt_bf16(const float* __restrict__ in,
                                                ushort* __restrict__ out, int n4) {
    int i = blockIdx.x * 256 + threadIdx.x;
    if (i >= n4) return;
    float4 v = ((const float4*)in)[i];
    ushort4 o;
    o.x = f2bf(v.x); o.y = f2bf(v.y); o.z = f2bf(v.z); o.w = f2bf(v.w);
    ((ushort4*)out)[i] = o;
}

// ---------------------------------------------------------------------------
// W [K=1024][N] fp32 -> WT bf16 rows [rowoff, rowoff+N) of [*][1024]
// ---------------------------------------------------------------------------
__global__ __launch_bounds__(256) void transpose_cvt(const float* __restrict__ W,
                                                     ushort* __restrict__ WT,
                                                     int N, int rowoff) {
    __shared__ float t[32][33];
    const int n0 = blockIdx.x * 32;
    const int k0 = blockIdx.y * 32;
    const int tx = threadIdx.x & 31;
    const int ty = threadIdx.x >> 5;  // 0..7
#pragma unroll
    for (int i = 0; i < 4; ++i)
        t[ty + 8 * i][tx] = W[(size_t)(k0 + ty + 8 * i) * N + n0 + tx];
    __syncthreads();
#pragma unroll
    for (int i = 0; i < 4; ++i)
        WT[(size_t)(rowoff + n0 + ty + 8 * i) * 1024 + k0 + tx] =
            f2bf(t[tx][ty + 8 * i]);
}

// ---------------------------------------------------------------------------
// bf16 MFMA GEMM: C[M,N] = A[M,K] bf16 @ BT[N,K] bf16; OT = float or ushort.
// 128x128 tile / 256 threads (4 waves 2x2), BK=32, 16x16x32 MFMA.
// ---------------------------------------------------------------------------
template <typename OT>
__global__ __launch_bounds__(256) void gemm_bf16(const ushort* __restrict__ A,
                                                 const ushort* __restrict__ BT,
                                                 OT* __restrict__ Cm,
                                                 int M, int N, int K) {
    __shared__ ushort As[128 * 32];
    __shared__ ushort Bs[128 * 32];
    const int tid = threadIdx.x;
    const int m0 = blockIdx.y * 128;
    const int n0 = blockIdx.x * 128;
    const int wave = tid >> 6;
    const int lane = tid & 63;
    const int wm = (wave >> 1) * 64;
    const int wn = (wave & 1) * 64;
    const int l15 = lane & 15;
    const int quad = lane >> 4;

    const int srow = tid >> 2;
    const int sc = (tid & 3) * 8;

    floatx4 acc[4][4] = {};

    const ushort* Ap0 = A + (size_t)(m0 + srow) * K + sc;
    const ushort* Ap1 = A + (size_t)(m0 + srow + 64) * K + sc;
    const ushort* Bp0 = BT + (size_t)(n0 + srow) * K + sc;
    const ushort* Bp1 = BT + (size_t)(n0 + srow + 64) * K + sc;

    for (int kt = 0; kt < K; kt += 32) {
        const int4 a0 = *(const int4*)(Ap0 + kt);
        const int4 a1 = *(const int4*)(Ap1 + kt);
        const int4 b0 = *(const int4*)(Bp0 + kt);
        const int4 b1 = *(const int4*)(Bp1 + kt);
        __syncthreads();
        *(int4*)&As[srow * 32 + sc] = a0;
        *(int4*)&As[(srow + 64) * 32 + sc] = a1;
        *(int4*)&Bs[srow * 32 + sc] = b0;
        *(int4*)&Bs[(srow + 64) * 32 + sc] = b1;
        __syncthreads();

        bf16x8 af[4], bfr[4];
#pragma unroll
        for (int i = 0; i < 4; ++i)
            af[i] = *(const bf16x8*)&As[(wm + i * 16 + l15) * 32 + quad * 8];
#pragma unroll
        for (int j = 0; j < 4; ++j)
            bfr[j] = *(const bf16x8*)&Bs[(wn + j * 16 + l15) * 32 + quad * 8];
#pragma unroll
        for (int i = 0; i < 4; ++i)
#pragma unroll
            for (int j = 0; j < 4; ++j)
                acc[i][j] = __builtin_amdgcn_mfma_f32_16x16x32_bf16(
                    af[i], bfr[j], acc[i][j], 0, 0, 0);
    }

#pragma unroll
    for (int i = 0; i < 4; ++i)
#pragma unroll
        for (int j = 0; j < 4; ++j)
#pragma unroll
            for (int r = 0; r < 4; ++r) {
                const size_t idx = (size_t)(m0 + wm + i * 16 + quad * 4 + r) * N +
                                   n0 + wn + j * 16 + l15;
                if constexpr (sizeof(OT) == 2)
                    Cm[idx] = f2bf(acc[i][j][r]);
                else
                    Cm[idx] = acc[i][j][r];
            }
}

// ---------------------------------------------------------------------------
// MFMA flash attention. Block = 256 thr (4 waves), 64-query tile per (b,h).
// Wave w owns query rows [w*16, w*16+16) for S, softmax state, and O.
// S: A=Q rows (natural), B=K rows (natural, acts as K^T). PV: A=P (same-wave
// LDS round-trip, bf16), B=V^T (staged transposed). All rows padded +8 bf16.
// ---------------------------------------------------------------------------
template <int D, int WIN>
__global__ __launch_bounds__(256) void attn_mfma(const ushort* __restrict__ act,
                                                 ushort* __restrict__ y,
                                                 float scale, int qoff, int koff,
                                                 int voff, int head_off) {
    constexpr int STR = D + 8;    // Qs/Ks row stride (ushorts)
    constexpr int PSTR = 72;      // Ps/VTs row stride
    constexpr int NKS = D / 32;   // MFMA k-steps for S
    constexpr int QCH = D / 8;    // 16B chunks per row

    __shared__ ushort Qs[64 * STR];
    __shared__ ushort Ks[64 * STR];
    __shared__ ushort VTs[64 * PSTR];
    __shared__ ushort Ps[64 * PSTR];

    const int t0 = blockIdx.x * 64;
    const int h = blockIdx.y;
    const int b = blockIdx.z;
    const int tid = threadIdx.x;
    const int wave = tid >> 6;
    const int lane = tid & 63;
    const int l15 = lane & 15;
    const int quad = lane >> 4;

    const ushort* qbase = act + (size_t)(b * T_ + t0) * NALL_ + qoff + h * D;
    const ushort* kbase = act + (size_t)(b * T_) * NALL_ + koff + h * D;
    const ushort* vbase = act + (size_t)(b * T_) * NALL_ + voff + h * HD_;

    // ---- stage Q (coalesced 16B chunks) ----
    for (int idx = tid; idx < 64 * QCH; idx += 256) {
        const int row = idx / QCH;
        const int ch = idx % QCH;
        *(int4*)&Qs[row * STR + ch * 8] =
            *(const int4*)(qbase + (size_t)row * NALL_ + ch * 8);
    }

    float m_i[4], l_i[4];
    floatx4 o_acc[4] = {};
#pragma unroll
    for (int r = 0; r < 4; ++r) { m_i[r] = -1e30f; l_i[r] = 0.f; }

    int k0s = t0 - WIN + 1;
    if (k0s < 0) k0s = 0;
    k0s &= ~63;

    const int qmin = t0 + wave * 16;

    for (int k0 = k0s; k0 <= t0; k0 += 64) {
        __syncthreads();  // all waves done with prev Ks/VTs
        // stage K tile
        for (int idx = tid; idx < 64 * QCH; idx += 256) {
            const int row = idx / QCH;
            const int ch = idx % QCH;
            *(int4*)&Ks[row * STR + ch * 8] =
                *(const int4*)(kbase + (size_t)(k0 + row) * NALL_ + ch * 8);
        }
        // stage V transposed
        for (int idx = tid; idx < 512; idx += 256) {
            const int kk = idx & 63;
            const int dseg = idx >> 6;  // 0..7 across 2 iterations
            ushort tmp[8];
            *(int4*)tmp = *(const int4*)(vbase + (size_t)(k0 + kk) * NALL_ + dseg * 8);
#pragma unroll
            for (int i = 0; i < 8; ++i)
                VTs[(dseg * 8 + i) * PSTR + kk] = tmp[i];
        }
        __syncthreads();

        // ---- S = Q K^T (wave's 16 rows x 64 keys) ----
        floatx4 s[4] = {};
#pragma unroll
        for (int ks = 0; ks < NKS; ++ks) {
            const bf16x8 a =
                *(const bf16x8*)&Qs[(wave * 16 + l15) * STR + ks * 32 + quad * 8];
#pragma unroll
            for (int j = 0; j < 4; ++j) {
                const bf16x8 bb =
                    *(const bf16x8*)&Ks[(j * 16 + l15) * STR + ks * 32 + quad * 8];
                s[j] = __builtin_amdgcn_mfma_f32_16x16x32_bf16(a, bb, s[j], 0, 0, 0);
            }
        }

        // ---- scale + mask ----
        const bool full = (k0 + 63 <= qmin) && ((qmin + 15) - k0 <= WIN - 1);
        if (full) {
#pragma unroll
            for (int j = 0; j < 4; ++j)
#pragma unroll
                for (int r = 0; r < 4; ++r) s[j][r] *= scale;
        } else {
#pragma unroll
            for (int j = 0; j < 4; ++j) {
                const int kj = k0 + j * 16 + l15;
#pragma unroll
                for (int r = 0; r < 4; ++r) {
                    const int rel = (qmin + quad * 4 + r) - kj;
                    s[j][r] = (rel < 0 || rel >= WIN) ? -1e30f : s[j][r] * scale;
                }
            }
        }

        // ---- online softmax (row = quad*4+r, reduce over 16-lane group) ----
#pragma unroll
        for (int r = 0; r < 4; ++r) {
            float rm = fmaxf(fmaxf(s[0][r], s[1][r]), fmaxf(s[2][r], s[3][r]));
            rm = fmaxf(rm, __shfl_xor(rm, 1, 64));
            rm = fmaxf(rm, __shfl_xor(rm, 2, 64));
            rm = fmaxf(rm, __shfl_xor(rm, 4, 64));
            rm = fmaxf(rm, __shfl_xor(rm, 8, 64));
            const float mn = fmaxf(m_i[r], rm);
            const float a = __expf(m_i[r] - mn);
            m_i[r] = mn;
            float sum = 0.f;
#pragma unroll
            for (int j = 0; j < 4; ++j) {
                const float e = __expf(s[j][r] - mn);
                sum += e;
                Ps[(wave * 16 + quad * 4 + r) * PSTR + j * 16 + l15] = f2bf(e);
            }
            sum += __shfl_xor(sum, 1, 64);
            sum += __shfl_xor(sum, 2, 64);
            sum += __shfl_xor(sum, 4, 64);
            sum += __shfl_xor(sum, 8, 64);
            l_i[r] = l_i[r] * a + sum;
#pragma unroll
            for (int j = 0; j < 4; ++j) o_acc[j][r] *= a;
        }

        // ---- PV: O += P @ V  (A=P same-wave rows, B=V^T) ----
#pragma unroll
        for (int kks = 0; kks < 2; ++kks) {
            const bf16x8 pa =
                *(const bf16x8*)&Ps[(wave * 16 + l15) * PSTR + kks * 32 + quad * 8];
#pragma unroll
            for (int j = 0; j < 4; ++j) {
                const bf16x8 vb =
                    *(const bf16x8*)&VTs[(j * 16 + l15) * PSTR + kks * 32 + quad * 8];
                o_acc[j] = __builtin_amdgcn_mfma_f32_16x16x32_bf16(pa, vb, o_acc[j],
                                                                   0, 0, 0);
            }
        }
    }

    // ---- epilogue: normalize, bf16 write into concatenated [B,T,C] ----
#pragma unroll
    for (int r = 0; r < 4; ++r) {
        const float inv = 1.f / l_i[r];
        ushort* yrow =
            y + (size_t)(b * T_ + t0 + wave * 16 + quad * 4 + r) * C_ + head_off +
            h * HD_;
#pragma unroll
        for (int j = 0; j < 4; ++j) yrow[j * 16 + l15] = f2bf(o_acc[j][r] * inv);
    }
}

// ---------------------------------------------------------------------------
extern "C" void kernel_launch(void* const* d_in, const int* in_sizes, int n_in,
                              void* d_out, int out_size, void* d_ws,
                              size_t ws_size, hipStream_t stream) {
    const float* x         = (const float*)d_in[0];
    const float* Wqk_short = (const float*)d_in[1];
    const float* Wv_short  = (const float*)d_in[2];
    const float* Wqk_long  = (const float*)d_in[3];
    const float* Wv_long   = (const float*)d_in[4];
    const float* Wproj     = (const float*)d_in[5];
    float* out = (float*)d_out;

    const int M = B_ * T_;  // 4096

    // workspace layout (all bf16 except final out)
    ushort* x16    = (ushort*)d_ws;                 // [4096][1024]
    ushort* WallT  = x16 + (size_t)M * C_;          // [3584][1024]
    ushort* WprojT = WallT + (size_t)NALL_ * C_;    // [1024][1024]
    ushort* yb16   = WprojT + (size_t)C_ * C_;      // [4096][1024]
    ushort* act    = yb16 + (size_t)M * C_;         // [4096][3584]
    // total ~54 MB

    dim3 blk(256);
    cvt_bf16<<<dim3(M * C_ / 4 / 256), blk, 0, stream>>>(x, x16, M * C_ / 4);
    transpose_cvt<<<dim3(512 / 32, 32), blk, 0, stream>>>(Wqk_short, WallT, 512, 0);
    transpose_cvt<<<dim3(512 / 32, 32), blk, 0, stream>>>(Wv_short, WallT, 512, 512);
    transpose_cvt<<<dim3(2048 / 32, 32), blk, 0, stream>>>(Wqk_long, WallT, 2048, 1024);
    transpose_cvt<<<dim3(512 / 32, 32), blk, 0, stream>>>(Wv_long, WallT, 512, 3072);
    transpose_cvt<<<dim3(1024 / 32, 32), blk, 0, stream>>>(Wproj, WprojT, 1024, 0);

    // fused input projections -> act bf16 [4096][3584]
    gemm_bf16<ushort><<<dim3(NALL_ / 128, M / 128), blk, 0, stream>>>(
        x16, WallT, act, M, NALL_, C_);

    // attention: act cols = [qs 0 | ks 256 | vs 512 | ql 1024 | kl 2048 | vl 3072]
    attn_mfma<DS_, WINS_><<<dim3(T_ / 64, HS_, B_), blk, 0, stream>>>(
        act, yb16, 0.17677669529663687f, 0, 256, 512, 0);
    attn_mfma<DL_, WINL_><<<dim3(T_ / 64, HL_, B_), blk, 0, stream>>>(
        act, yb16, 0.08838834764831843f, 1024, 2048, 3072, HS_ * HD_);

    // output projection (fp32 out)
    gemm_bf16<float><<<dim3(C_ / 128, M / 128), blk, 0, stream>>>(
        yb16, WprojT, out, M, C_, C_);
}

// Round 5
// 256.792 us; speedup vs baseline: 15.9476x; 1.0086x over previous
//
#include <hip/hip_runtime.h>
#include <math.h>

// Problem constants (match reference)
#define B_    2
#define T_    2048
#define C_    1024
#define HS_   8
#define DS_   32
#define HL_   8
#define DL_   128
#define HD_   64
#define WINS_ 256
#define WINL_ 1024
#define NALL_ 3584   // 512 (qk_s) + 512 (v_s) + 2048 (qk_l) + 512 (v_l)

typedef __bf16 bf16x8 __attribute__((ext_vector_type(8)));
typedef float floatx4 __attribute__((ext_vector_type(4)));

__device__ __forceinline__ ushort f2bf(float f) {
    union { float f; unsigned u; } v; v.f = f;
    unsigned r = v.u + 0x7fff + ((v.u >> 16) & 1);  // RNE
    return (ushort)(r >> 16);
}

// async global->LDS, 16B per lane. LDS dest = wave-uniform base + lane*16.
__device__ __forceinline__ void gload_lds16(const void* g, void* l) {
    __builtin_amdgcn_global_load_lds(
        (const __attribute__((address_space(1))) void*)g,
        (__attribute__((address_space(3))) void*)l, 16, 0, 0);
}

// ---------------------------------------------------------------------------
// x (fp32) -> bf16, vectorized
// ---------------------------------------------------------------------------
__global__ __launch_bounds__(256) void cvt_bf16(const float* __restrict__ in,
                                                ushort* __restrict__ out, int n4) {
    int i = blockIdx.x * 256 + threadIdx.x;
    if (i >= n4) return;
    float4 v = ((const float4*)in)[i];
    ushort4 o;
    o.x = f2bf(v.x); o.y = f2bf(v.y); o.z = f2bf(v.z); o.w = f2bf(v.w);
    ((ushort4*)out)[i] = o;
}

// ---------------------------------------------------------------------------
// W [K=1024][N] fp32 -> WT bf16 rows [rowoff, rowoff+N) of [*][1024]
// ---------------------------------------------------------------------------
__global__ __launch_bounds__(256) void transpose_cvt(const float* __restrict__ W,
                                                     ushort* __restrict__ WT,
                                                     int N, int rowoff) {
    __shared__ float t[32][33];
    const int n0 = blockIdx.x * 32;
    const int k0 = blockIdx.y * 32;
    const int tx = threadIdx.x & 31;
    const int ty = threadIdx.x >> 5;  // 0..7
#pragma unroll
    for (int i = 0; i < 4; ++i)
        t[ty + 8 * i][tx] = W[(size_t)(k0 + ty + 8 * i) * N + n0 + tx];
    __syncthreads();
#pragma unroll
    for (int i = 0; i < 4; ++i)
        WT[(size_t)(rowoff + n0 + ty + 8 * i) * 1024 + k0 + tx] =
            f2bf(t[tx][ty + 8 * i]);
}

// ---------------------------------------------------------------------------
// bf16 MFMA GEMM: C[M,N] = A[M,K] bf16 @ BT[N,K] bf16; OT = float or ushort.
// 128x128 tile / 256 threads (4 waves 2x2), BK=32, 16x16x32 MFMA.
// Staging via global_load_lds dwordx4 (m97 pattern): LDS layout is
// lane-contiguous (byte offset = tid*16), so per-wave base = &As[wave*512].
// ---------------------------------------------------------------------------
template <typename OT>
__global__ __launch_bounds__(256) void gemm_bf16(const ushort* __restrict__ A,
                                                 const ushort* __restrict__ BT,
                                                 OT* __restrict__ Cm,
                                                 int M, int N, int K) {
    __shared__ ushort As[128 * 32];
    __shared__ ushort Bs[128 * 32];
    const int tid = threadIdx.x;
    const int m0 = blockIdx.y * 128;
    const int n0 = blockIdx.x * 128;
    const int wave = tid >> 6;
    const int lane = tid & 63;
    const int wm = (wave >> 1) * 64;
    const int wn = (wave & 1) * 64;
    const int l15 = lane & 15;
    const int quad = lane >> 4;

    const int srow = tid >> 2;        // global row within tile half
    const int sc = (tid & 3) * 8;     // 16B chunk within row

    floatx4 acc[4][4] = {};

    const ushort* Ap0 = A + (size_t)(m0 + srow) * K + sc;
    const ushort* Ap1 = A + (size_t)(m0 + srow + 64) * K + sc;
    const ushort* Bp0 = BT + (size_t)(n0 + srow) * K + sc;
    const ushort* Bp1 = BT + (size_t)(n0 + srow + 64) * K + sc;

    // wave-uniform LDS bases (lane i lands at base + i*16 bytes = tid*16)
    ushort* AsB0 = &As[wave * 512];
    ushort* AsB1 = &As[wave * 512 + 2048];
    ushort* BsB0 = &Bs[wave * 512];
    ushort* BsB1 = &Bs[wave * 512 + 2048];

    for (int kt = 0; kt < K; kt += 32) {
        __syncthreads();  // prev iter's frag reads done
        gload_lds16(Ap0 + kt, AsB0);
        gload_lds16(Ap1 + kt, AsB1);
        gload_lds16(Bp0 + kt, BsB0);
        gload_lds16(Bp1 + kt, BsB1);
        __syncthreads();  // vmcnt drain + visibility

        bf16x8 af[4], bfr[4];
#pragma unroll
        for (int i = 0; i < 4; ++i)
            af[i] = *(const bf16x8*)&As[(wm + i * 16 + l15) * 32 + quad * 8];
#pragma unroll
        for (int j = 0; j < 4; ++j)
            bfr[j] = *(const bf16x8*)&Bs[(wn + j * 16 + l15) * 32 + quad * 8];
#pragma unroll
        for (int i = 0; i < 4; ++i)
#pragma unroll
            for (int j = 0; j < 4; ++j)
                acc[i][j] = __builtin_amdgcn_mfma_f32_16x16x32_bf16(
                    af[i], bfr[j], acc[i][j], 0, 0, 0);
    }

#pragma unroll
    for (int i = 0; i < 4; ++i)
#pragma unroll
        for (int j = 0; j < 4; ++j)
#pragma unroll
            for (int r = 0; r < 4; ++r) {
                const size_t idx = (size_t)(m0 + wm + i * 16 + quad * 4 + r) * N +
                                   n0 + wn + j * 16 + l15;
                if constexpr (sizeof(OT) == 2)
                    Cm[idx] = f2bf(acc[i][j][r]);
                else
                    Cm[idx] = acc[i][j][r];
            }
}

// ---------------------------------------------------------------------------
// MFMA flash attention, fused short+long. Block = 256 thr (4 waves),
// 64-query tile. Wave w owns query rows [w*16, w*16+16).
// Q frags hoisted to registers (staged once through Ks). LDS (dynamic):
// Ks 64*(D+8) | VTs 64*72 | Ps 64*72  -> long 35840 B => 4 blocks/CU.
// ---------------------------------------------------------------------------
template <int D, int WIN>
__device__ __forceinline__ void attn_dev(const ushort* __restrict__ act,
                                         ushort* __restrict__ y, float scale,
                                         int qoff, int koff, int voff,
                                         int head_off, int h, ushort* lds) {
    constexpr int STR = D + 8;    // Ks row stride (ushorts)
    constexpr int PSTR = 72;      // Ps/VTs row stride
    constexpr int NKS = D / 32;   // MFMA k-steps for S
    constexpr int QCH = D / 8;    // 16B chunks per row

    ushort* Ks = lds;                    // 64*STR
    ushort* VTs = Ks + 64 * STR;         // 64*72
    ushort* Ps = VTs + 64 * PSTR;        // 64*72

    const int t0 = blockIdx.x * 64;
    const int b = blockIdx.z;
    const int tid = threadIdx.x;
    const int wave = tid >> 6;
    const int lane = tid & 63;
    const int l15 = lane & 15;
    const int quad = lane >> 4;

    const ushort* qbase = act + (size_t)(b * T_ + t0) * NALL_ + qoff + h * D;
    const ushort* kbase = act + (size_t)(b * T_) * NALL_ + koff + h * D;
    const ushort* vbase = act + (size_t)(b * T_) * NALL_ + voff + h * HD_;

    // ---- stage Q once (through Ks), hoist frags to registers ----
    for (int idx = tid; idx < 64 * QCH; idx += 256) {
        const int row = idx / QCH;
        const int ch = idx % QCH;
        *(int4*)&Ks[row * STR + ch * 8] =
            *(const int4*)(qbase + (size_t)row * NALL_ + ch * 8);
    }
    __syncthreads();
    bf16x8 qa[NKS];
#pragma unroll
    for (int ks = 0; ks < NKS; ++ks)
        qa[ks] = *(const bf16x8*)&Ks[(wave * 16 + l15) * STR + ks * 32 + quad * 8];

    float m_i[4], l_i[4];
    floatx4 o_acc[4] = {};
#pragma unroll
    for (int r = 0; r < 4; ++r) { m_i[r] = -1e30f; l_i[r] = 0.f; }

    int k0s = t0 - WIN + 1;
    if (k0s < 0) k0s = 0;
    k0s &= ~63;

    const int qmin = t0 + wave * 16;

    for (int k0 = k0s; k0 <= t0; k0 += 64) {
        __syncthreads();  // all waves done with prev Ks/VTs (and Q frag reads)
        // stage K tile
        for (int idx = tid; idx < 64 * QCH; idx += 256) {
            const int row = idx / QCH;
            const int ch = idx % QCH;
            *(int4*)&Ks[row * STR + ch * 8] =
                *(const int4*)(kbase + (size_t)(k0 + row) * NALL_ + ch * 8);
        }
        // stage V transposed
        for (int idx = tid; idx < 512; idx += 256) {
            const int kk = idx & 63;
            const int dseg = idx >> 6;
            ushort tmp[8];
            *(int4*)tmp =
                *(const int4*)(vbase + (size_t)(k0 + kk) * NALL_ + dseg * 8);
#pragma unroll
            for (int i = 0; i < 8; ++i)
                VTs[(dseg * 8 + i) * PSTR + kk] = tmp[i];
        }
        __syncthreads();

        // ---- S = Q K^T (wave's 16 rows x 64 keys) ----
        floatx4 s[4] = {};
#pragma unroll
        for (int ks = 0; ks < NKS; ++ks) {
#pragma unroll
            for (int j = 0; j < 4; ++j) {
                const bf16x8 bb =
                    *(const bf16x8*)&Ks[(j * 16 + l15) * STR + ks * 32 + quad * 8];
                s[j] = __builtin_amdgcn_mfma_f32_16x16x32_bf16(qa[ks], bb, s[j],
                                                               0, 0, 0);
            }
        }

        // ---- scale + mask ----
        const bool full = (k0 + 63 <= qmin) && ((qmin + 15) - k0 <= WIN - 1);
        if (full) {
#pragma unroll
            for (int j = 0; j < 4; ++j)
#pragma unroll
                for (int r = 0; r < 4; ++r) s[j][r] *= scale;
        } else {
#pragma unroll
            for (int j = 0; j < 4; ++j) {
                const int kj = k0 + j * 16 + l15;
#pragma unroll
                for (int r = 0; r < 4; ++r) {
                    const int rel = (qmin + quad * 4 + r) - kj;
                    s[j][r] = (rel < 0 || rel >= WIN) ? -1e30f : s[j][r] * scale;
                }
            }
        }

        // ---- online softmax (row = quad*4+r, reduce over 16-lane group) ----
#pragma unroll
        for (int r = 0; r < 4; ++r) {
            float rm = fmaxf(fmaxf(s[0][r], s[1][r]), fmaxf(s[2][r], s[3][r]));
            rm = fmaxf(rm, __shfl_xor(rm, 1, 64));
            rm = fmaxf(rm, __shfl_xor(rm, 2, 64));
            rm = fmaxf(rm, __shfl_xor(rm, 4, 64));
            rm = fmaxf(rm, __shfl_xor(rm, 8, 64));
            const float mn = fmaxf(m_i[r], rm);
            const float a = __expf(m_i[r] - mn);
            m_i[r] = mn;
            float sum = 0.f;
#pragma unroll
            for (int j = 0; j < 4; ++j) {
                const float e = __expf(s[j][r] - mn);
                sum += e;
                Ps[(wave * 16 + quad * 4 + r) * PSTR + j * 16 + l15] = f2bf(e);
            }
            sum += __shfl_xor(sum, 1, 64);
            sum += __shfl_xor(sum, 2, 64);
            sum += __shfl_xor(sum, 4, 64);
            sum += __shfl_xor(sum, 8, 64);
            l_i[r] = l_i[r] * a + sum;
#pragma unroll
            for (int j = 0; j < 4; ++j) o_acc[j][r] *= a;
        }

        // ---- PV: O += P @ V  (A=P same-wave rows, B=V^T) ----
#pragma unroll
        for (int kks = 0; kks < 2; ++kks) {
            const bf16x8 pa =
                *(const bf16x8*)&Ps[(wave * 16 + l15) * PSTR + kks * 32 + quad * 8];
#pragma unroll
            for (int j = 0; j < 4; ++j) {
                const bf16x8 vb =
                    *(const bf16x8*)&VTs[(j * 16 + l15) * PSTR + kks * 32 + quad * 8];
                o_acc[j] = __builtin_amdgcn_mfma_f32_16x16x32_bf16(pa, vb, o_acc[j],
                                                                   0, 0, 0);
            }
        }
    }

    // ---- epilogue: normalize, bf16 write into concatenated [B,T,C] ----
#pragma unroll
    for (int r = 0; r < 4; ++r) {
        const float inv = 1.f / l_i[r];
        ushort* yrow =
            y + (size_t)(b * T_ + t0 + wave * 16 + quad * 4 + r) * C_ + head_off +
            h * HD_;
#pragma unroll
        for (int j = 0; j < 4; ++j) yrow[j * 16 + l15] = f2bf(o_acc[j][r] * inv);
    }
}

__global__ __launch_bounds__(256) void attn_fused(const ushort* __restrict__ act,
                                                  ushort* __restrict__ y) {
    extern __shared__ ushort smem[];
    const int hy = blockIdx.y;
    if (hy < HS_) {
        attn_dev<DS_, WINS_>(act, y, 0.17677669529663687f, 0, 256, 512, 0, hy,
                             smem);
    } else {
        attn_dev<DL_, WINL_>(act, y, 0.08838834764831843f, 1024, 2048, 3072,
                             HS_ * HD_, hy - HS_, smem);
    }
}

// ---------------------------------------------------------------------------
extern "C" void kernel_launch(void* const* d_in, const int* in_sizes, int n_in,
                              void* d_out, int out_size, void* d_ws,
                              size_t ws_size, hipStream_t stream) {
    const float* x         = (const float*)d_in[0];
    const float* Wqk_short = (const float*)d_in[1];
    const float* Wv_short  = (const float*)d_in[2];
    const float* Wqk_long  = (const float*)d_in[3];
    const float* Wv_long   = (const float*)d_in[4];
    const float* Wproj     = (const float*)d_in[5];
    float* out = (float*)d_out;

    const int M = B_ * T_;  // 4096

    // workspace layout (all bf16 except final out)
    ushort* x16    = (ushort*)d_ws;                 // [4096][1024]
    ushort* WallT  = x16 + (size_t)M * C_;          // [3584][1024]
    ushort* WprojT = WallT + (size_t)NALL_ * C_;    // [1024][1024]
    ushort* yb16   = WprojT + (size_t)C_ * C_;      // [4096][1024]
    ushort* act    = yb16 + (size_t)M * C_;         // [4096][3584]

    dim3 blk(256);
    cvt_bf16<<<dim3(M * C_ / 4 / 256), blk, 0, stream>>>(x, x16, M * C_ / 4);
    transpose_cvt<<<dim3(512 / 32, 32), blk, 0, stream>>>(Wqk_short, WallT, 512, 0);
    transpose_cvt<<<dim3(512 / 32, 32), blk, 0, stream>>>(Wv_short, WallT, 512, 512);
    transpose_cvt<<<dim3(2048 / 32, 32), blk, 0, stream>>>(Wqk_long, WallT, 2048, 1024);
    transpose_cvt<<<dim3(512 / 32, 32), blk, 0, stream>>>(Wv_long, WallT, 512, 3072);
    transpose_cvt<<<dim3(1024 / 32, 32), blk, 0, stream>>>(Wproj, WprojT, 1024, 0);

    // fused input projections -> act bf16 [4096][3584]
    gemm_bf16<ushort><<<dim3(NALL_ / 128, M / 128), blk, 0, stream>>>(
        x16, WallT, act, M, NALL_, C_);

    // fused attention (short heads y=0..7, long heads y=8..15)
    const int attn_lds = 64 * (DL_ + 8) * 2 + 64 * 72 * 2 * 2;  // 35840 B
    attn_fused<<<dim3(T_ / 64, HS_ + HL_, B_), blk, attn_lds, stream>>>(act,
                                                                        yb16);

    // output projection (fp32 out)
    gemm_bf16<float><<<dim3(C_ / 128, M / 128), blk, 0, stream>>>(
        yb16, WprojT, out, M, C_, C_);
}

// Round 7
// 251.869 us; speedup vs baseline: 16.2593x; 1.0195x over previous
//
#include <hip/hip_runtime.h>
#include <math.h>

// Problem constants (match reference)
#define B_    2
#define T_    2048
#define C_    1024
#define HS_   8
#define DS_   32
#define HL_   8
#define DL_   128
#define HD_   64
#define WINS_ 256
#define WINL_ 1024
#define NALL_ 3584   // 512 (qk_s) + 512 (v_s) + 2048 (qk_l) + 512 (v_l)

typedef __bf16 bf16x8 __attribute__((ext_vector_type(8)));
typedef float floatx4 __attribute__((ext_vector_type(4)));

__device__ __forceinline__ ushort f2bf(float f) {
    union { float f; unsigned u; } v; v.f = f;
    unsigned r = v.u + 0x7fff + ((v.u >> 16) & 1);  // RNE
    return (ushort)(r >> 16);
}

// async global->LDS, 16B per lane. LDS dest = wave-uniform base + lane*16.
__device__ __forceinline__ void gload_lds16(const void* g, void* l) {
    __builtin_amdgcn_global_load_lds(
        (const __attribute__((address_space(1))) void*)g,
        (__attribute__((address_space(3))) void*)l, 16, 0, 0);
}

// ---------------------------------------------------------------------------
// Fused prep: blocks [0,4096) convert x fp32->bf16; blocks [4096,8704)
// transpose+convert the five weight matrices (K=1024 each).
// ---------------------------------------------------------------------------
__global__ __launch_bounds__(256) void prep(
    const float* __restrict__ x, ushort* __restrict__ x16,
    const float* __restrict__ Wqk_s, const float* __restrict__ Wv_s,
    const float* __restrict__ Wqk_l, const float* __restrict__ Wv_l,
    const float* __restrict__ Wproj, ushort* __restrict__ WallT,
    ushort* __restrict__ WprojT) {
    __shared__ float t[32][33];
    int bid = blockIdx.x;
    if (bid < 4096) {
        const int i = bid * 256 + threadIdx.x;
        float4 v = ((const float4*)x)[i];
        ushort4 o;
        o.x = f2bf(v.x); o.y = f2bf(v.y); o.z = f2bf(v.z); o.w = f2bf(v.w);
        ((ushort4*)x16)[i] = o;
        return;
    }
    bid -= 4096;
    const float* W; ushort* WT; int N, rowoff;
    if (bid < 512)       { W = Wqk_s; WT = WallT;  N = 512;  rowoff = 0; }
    else if (bid < 1024) { bid -= 512;  W = Wv_s;  WT = WallT;  N = 512;  rowoff = 512; }
    else if (bid < 3072) { bid -= 1024; W = Wqk_l; WT = WallT;  N = 2048; rowoff = 1024; }
    else if (bid < 3584) { bid -= 3072; W = Wv_l;  WT = WallT;  N = 512;  rowoff = 3072; }
    else                 { bid -= 3584; W = Wproj; WT = WprojT; N = 1024; rowoff = 0; }
    const int nt = N / 32;
    const int n0 = (bid % nt) * 32;
    const int k0 = (bid / nt) * 32;
    const int tx = threadIdx.x & 31;
    const int ty = threadIdx.x >> 5;  // 0..7
#pragma unroll
    for (int i = 0; i < 4; ++i)
        t[ty + 8 * i][tx] = W[(size_t)(k0 + ty + 8 * i) * N + n0 + tx];
    __syncthreads();
#pragma unroll
    for (int i = 0; i < 4; ++i)
        WT[(size_t)(rowoff + n0 + ty + 8 * i) * 1024 + k0 + tx] =
            f2bf(t[tx][ty + 8 * i]);
}

// ---------------------------------------------------------------------------
// bf16 MFMA GEMM: C[M,N] = A[M,K] bf16 @ BT[N,K] bf16; OT = float or ushort.
// 128x128 tile / 256 threads (4 waves 2x2), BK=32, 16x16x32 MFMA.
// Staging via global_load_lds dwordx4 (m97 pattern).
// ---------------------------------------------------------------------------
template <typename OT>
__global__ __launch_bounds__(256) void gemm_bf16(const ushort* __restrict__ A,
                                                 const ushort* __restrict__ BT,
                                                 OT* __restrict__ Cm,
                                                 int M, int N, int K) {
    __shared__ ushort As[128 * 32];
    __shared__ ushort Bs[128 * 32];
    const int tid = threadIdx.x;
    const int m0 = blockIdx.y * 128;
    const int n0 = blockIdx.x * 128;
    const int wave = tid >> 6;
    const int lane = tid & 63;
    const int wm = (wave >> 1) * 64;
    const int wn = (wave & 1) * 64;
    const int l15 = lane & 15;
    const int quad = lane >> 4;

    const int srow = tid >> 2;
    const int sc = (tid & 3) * 8;

    floatx4 acc[4][4] = {};

    const ushort* Ap0 = A + (size_t)(m0 + srow) * K + sc;
    const ushort* Ap1 = A + (size_t)(m0 + srow + 64) * K + sc;
    const ushort* Bp0 = BT + (size_t)(n0 + srow) * K + sc;
    const ushort* Bp1 = BT + (size_t)(n0 + srow + 64) * K + sc;

    ushort* AsB0 = &As[wave * 512];
    ushort* AsB1 = &As[wave * 512 + 2048];
    ushort* BsB0 = &Bs[wave * 512];
    ushort* BsB1 = &Bs[wave * 512 + 2048];

    for (int kt = 0; kt < K; kt += 32) {
        __syncthreads();
        gload_lds16(Ap0 + kt, AsB0);
        gload_lds16(Ap1 + kt, AsB1);
        gload_lds16(Bp0 + kt, BsB0);
        gload_lds16(Bp1 + kt, BsB1);
        __syncthreads();

        bf16x8 af[4], bfr[4];
#pragma unroll
        for (int i = 0; i < 4; ++i)
            af[i] = *(const bf16x8*)&As[(wm + i * 16 + l15) * 32 + quad * 8];
#pragma unroll
        for (int j = 0; j < 4; ++j)
            bfr[j] = *(const bf16x8*)&Bs[(wn + j * 16 + l15) * 32 + quad * 8];
#pragma unroll
        for (int i = 0; i < 4; ++i)
#pragma unroll
            for (int j = 0; j < 4; ++j)
                acc[i][j] = __builtin_amdgcn_mfma_f32_16x16x32_bf16(
                    af[i], bfr[j], acc[i][j], 0, 0, 0);
    }

#pragma unroll
    for (int i = 0; i < 4; ++i)
#pragma unroll
        for (int j = 0; j < 4; ++j)
#pragma unroll
            for (int r = 0; r < 4; ++r) {
                const size_t idx = (size_t)(m0 + wm + i * 16 + quad * 4 + r) * N +
                                   n0 + wn + j * 16 + l15;
                if constexpr (sizeof(OT) == 2)
                    Cm[idx] = f2bf(acc[i][j][r]);
                else
                    Cm[idx] = acc[i][j][r];
            }
}

// ---------------------------------------------------------------------------
// V transpose: act V-columns -> vt[b][gh][d][T] (keys contiguous).
// gh 0..7 = short heads (cols 512+), gh 8..15 = long heads (cols 3072+).
// FIX(R6): each thread loads TWO int4 chunks (512 chunks / 256 threads) —
// R5 loaded only cols 0..31, leaving tile[][32..63] uninitialized -> NaN.
// ---------------------------------------------------------------------------
__global__ __launch_bounds__(256) void vtrans(const ushort* __restrict__ act,
                                              ushort* __restrict__ vt) {
    __shared__ ushort tile[64][72];
    const int t0 = blockIdx.x * 64;
    const int gh = blockIdx.y;
    const int b = blockIdx.z;
    const int col = (gh < 8) ? (512 + gh * 64) : (3072 + (gh - 8) * 64);
    const ushort* src = act + (size_t)(b * T_ + t0) * NALL_ + col;
    {
        const int tr = threadIdx.x >> 2;
        const int ch = threadIdx.x & 3;
        *(int4*)&tile[tr][ch * 8] =
            *(const int4*)(src + (size_t)tr * NALL_ + ch * 8);
        *(int4*)&tile[tr][(ch + 4) * 8] =
            *(const int4*)(src + (size_t)tr * NALL_ + (ch + 4) * 8);
    }
    __syncthreads();
    const int d = threadIdx.x >> 2;
    const int ts = (threadIdx.x & 3) * 16;
    ushort tmp[16];
#pragma unroll
    for (int i = 0; i < 16; ++i) tmp[i] = tile[ts + i][d];
    ushort* dst = vt + ((size_t)(b * 16 + gh) * HD_ + d) * T_ + t0 + ts;
    *(int4*)dst = *(int4*)tmp;
    *(int4*)(dst + 8) = *(int4*)(tmp + 8);
}

// ---------------------------------------------------------------------------
// MFMA flash attention, fused, register-prefetch pipelined.
// Block = 256 thr (4 waves), 64-query tile; wave w owns rows [w*16,w*16+16).
// Tile k+1's K/V are preloaded into VGPRs while tile k computes.
// V comes pre-transposed from vt (no per-tile scatter).
// LDS: Ks 64*(D+8) | VTs 64*72 | Ps 64*72 -> long 35840 B => 4 blocks/CU.
// ---------------------------------------------------------------------------
template <int D, int WIN>
__device__ __forceinline__ void attn_dev(const ushort* __restrict__ act,
                                         const ushort* __restrict__ vt,
                                         ushort* __restrict__ y, float scale,
                                         int qoff, int koff, int head_off,
                                         int h, int gh, ushort* lds) {
    constexpr int STR = D + 8;    // Ks row stride (ushorts)
    constexpr int PSTR = 72;      // Ps/VTs row stride
    constexpr int NKS = D / 32;   // MFMA k-steps for S
    constexpr int QCH = D / 8;    // int4 chunks per K/Q row
    constexpr int NKLD = (64 * QCH) / 256;  // K int4 loads per thread

    ushort* Ks = lds;                 // 64*STR
    ushort* VTs = Ks + 64 * STR;      // 64*72
    ushort* Ps = VTs + 64 * PSTR;     // 64*72

    const int t0 = blockIdx.x * 64;
    const int b = blockIdx.z;
    const int tid = threadIdx.x;
    const int wave = tid >> 6;
    const int lane = tid & 63;
    const int l15 = lane & 15;
    const int quad = lane >> 4;

    const ushort* qbase = act + (size_t)(b * T_ + t0) * NALL_ + qoff + h * D;
    const ushort* kbase = act + (size_t)(b * T_) * NALL_ + koff + h * D;
    const ushort* vtb = vt + (size_t)((b * 16 + gh) * HD_) * T_;

    int k0s = t0 - WIN + 1;
    if (k0s < 0) k0s = 0;
    k0s &= ~63;

    // per-thread staging coordinates (loop-invariant)
    int krow[NKLD], kch[NKLD];
#pragma unroll
    for (int i = 0; i < NKLD; ++i) {
        const int idx = tid + 256 * i;
        krow[i] = idx / QCH;
        kch[i] = idx % QCH;
    }
    const int vd0 = tid >> 3, vc0 = (tid & 7) * 8;
    const int vd1 = (tid + 256) >> 3, vc1 = ((tid + 256) & 7) * 8;

    // ---- prefetch tile k0s into registers ----
    int4 kreg[NKLD], vreg0, vreg1;
#pragma unroll
    for (int i = 0; i < NKLD; ++i)
        kreg[i] = *(const int4*)(kbase + (size_t)(k0s + krow[i]) * NALL_ + kch[i] * 8);
    vreg0 = *(const int4*)(vtb + (size_t)vd0 * T_ + k0s + vc0);
    vreg1 = *(const int4*)(vtb + (size_t)vd1 * T_ + k0s + vc1);

    // ---- stage Q once (through Ks), hoist frags to registers ----
    for (int idx = tid; idx < 64 * QCH; idx += 256) {
        const int row = idx / QCH;
        const int ch = idx % QCH;
        *(int4*)&Ks[row * STR + ch * 8] =
            *(const int4*)(qbase + (size_t)row * NALL_ + ch * 8);
    }
    __syncthreads();
    bf16x8 qa[NKS];
#pragma unroll
    for (int ks = 0; ks < NKS; ++ks)
        qa[ks] = *(const bf16x8*)&Ks[(wave * 16 + l15) * STR + ks * 32 + quad * 8];

    float m_i[4], l_i[4];
    floatx4 o_acc[4] = {};
#pragma unroll
    for (int r = 0; r < 4; ++r) { m_i[r] = -1e30f; l_i[r] = 0.f; }

    const int qmin = t0 + wave * 16;

    for (int k0 = k0s; k0 <= t0; k0 += 64) {
        __syncthreads();  // all waves done with Ks (incl. qa) / VTs
        // regs -> LDS
#pragma unroll
        for (int i = 0; i < NKLD; ++i)
            *(int4*)&Ks[krow[i] * STR + kch[i] * 8] = kreg[i];
        *(int4*)&VTs[vd0 * PSTR + vc0] = vreg0;
        *(int4*)&VTs[vd1 * PSTR + vc1] = vreg1;
        __syncthreads();
        // prefetch next tile (overlaps with compute below)
        if (k0 + 64 <= t0) {
#pragma unroll
            for (int i = 0; i < NKLD; ++i)
                kreg[i] = *(const int4*)(kbase +
                                         (size_t)(k0 + 64 + krow[i]) * NALL_ +
                                         kch[i] * 8);
            vreg0 = *(const int4*)(vtb + (size_t)vd0 * T_ + k0 + 64 + vc0);
            vreg1 = *(const int4*)(vtb + (size_t)vd1 * T_ + k0 + 64 + vc1);
        }

        // ---- S = Q K^T (wave's 16 rows x 64 keys) ----
        floatx4 s[4] = {};
#pragma unroll
        for (int ks = 0; ks < NKS; ++ks) {
#pragma unroll
            for (int j = 0; j < 4; ++j) {
                const bf16x8 bb =
                    *(const bf16x8*)&Ks[(j * 16 + l15) * STR + ks * 32 + quad * 8];
                s[j] = __builtin_amdgcn_mfma_f32_16x16x32_bf16(qa[ks], bb, s[j],
                                                               0, 0, 0);
            }
        }

        // ---- scale + mask ----
        const bool full = (k0 + 63 <= qmin) && ((qmin + 15) - k0 <= WIN - 1);
        if (full) {
#pragma unroll
            for (int j = 0; j < 4; ++j)
#pragma unroll
                for (int r = 0; r < 4; ++r) s[j][r] *= scale;
        } else {
#pragma unroll
            for (int j = 0; j < 4; ++j) {
                const int kj = k0 + j * 16 + l15;
#pragma unroll
                for (int r = 0; r < 4; ++r) {
                    const int rel = (qmin + quad * 4 + r) - kj;
                    s[j][r] = (rel < 0 || rel >= WIN) ? -1e30f : s[j][r] * scale;
                }
            }
        }

        // ---- online softmax ----
#pragma unroll
        for (int r = 0; r < 4; ++r) {
            float rm = fmaxf(fmaxf(s[0][r], s[1][r]), fmaxf(s[2][r], s[3][r]));
            rm = fmaxf(rm, __shfl_xor(rm, 1, 64));
            rm = fmaxf(rm, __shfl_xor(rm, 2, 64));
            rm = fmaxf(rm, __shfl_xor(rm, 4, 64));
            rm = fmaxf(rm, __shfl_xor(rm, 8, 64));
            const float mn = fmaxf(m_i[r], rm);
            const float a = __expf(m_i[r] - mn);
            m_i[r] = mn;
            float sum = 0.f;
#pragma unroll
            for (int j = 0; j < 4; ++j) {
                const float e = __expf(s[j][r] - mn);
                sum += e;
                Ps[(wave * 16 + quad * 4 + r) * PSTR + j * 16 + l15] = f2bf(e);
            }
            sum += __shfl_xor(sum, 1, 64);
            sum += __shfl_xor(sum, 2, 64);
            sum += __shfl_xor(sum, 4, 64);
            sum += __shfl_xor(sum, 8, 64);
            l_i[r] = l_i[r] * a + sum;
#pragma unroll
            for (int j = 0; j < 4; ++j) o_acc[j][r] *= a;
        }

        // ---- PV: O += P @ V ----
#pragma unroll
        for (int kks = 0; kks < 2; ++kks) {
            const bf16x8 pa =
                *(const bf16x8*)&Ps[(wave * 16 + l15) * PSTR + kks * 32 + quad * 8];
#pragma unroll
            for (int j = 0; j < 4; ++j) {
                const bf16x8 vb =
                    *(const bf16x8*)&VTs[(j * 16 + l15) * PSTR + kks * 32 + quad * 8];
                o_acc[j] = __builtin_amdgcn_mfma_f32_16x16x32_bf16(pa, vb, o_acc[j],
                                                                   0, 0, 0);
            }
        }
    }

    // ---- epilogue ----
#pragma unroll
    for (int r = 0; r < 4; ++r) {
        const float inv = 1.f / l_i[r];
        ushort* yrow =
            y + (size_t)(b * T_ + t0 + wave * 16 + quad * 4 + r) * C_ + head_off +
            h * HD_;
#pragma unroll
        for (int j = 0; j < 4; ++j) yrow[j * 16 + l15] = f2bf(o_acc[j][r] * inv);
    }
}

// Long heads on y=0..7 (dispatch first; short blocks backfill the tail).
__global__ __launch_bounds__(256, 4) void attn_fused(
    const ushort* __restrict__ act, const ushort* __restrict__ vt,
    ushort* __restrict__ y) {
    extern __shared__ ushort smem[];
    const int hy = blockIdx.y;
    if (hy < HL_) {
        attn_dev<DL_, WINL_>(act, vt, y, 0.08838834764831843f, 1024, 2048,
                             HS_ * HD_, hy, 8 + hy, smem);
    } else {
        attn_dev<DS_, WINS_>(act, vt, y, 0.17677669529663687f, 0, 256, 0,
                             hy - HL_, hy - HL_, smem);
    }
}

// ---------------------------------------------------------------------------
extern "C" void kernel_launch(void* const* d_in, const int* in_sizes, int n_in,
                              void* d_out, int out_size, void* d_ws,
                              size_t ws_size, hipStream_t stream) {
    const float* x         = (const float*)d_in[0];
    const float* Wqk_short = (const float*)d_in[1];
    const float* Wv_short  = (const float*)d_in[2];
    const float* Wqk_long  = (const float*)d_in[3];
    const float* Wv_long   = (const float*)d_in[4];
    const float* Wproj     = (const float*)d_in[5];
    float* out = (float*)d_out;

    const int M = B_ * T_;  // 4096

    // workspace layout (all bf16 except final out)
    ushort* x16    = (ushort*)d_ws;                 // [4096][1024]
    ushort* WallT  = x16 + (size_t)M * C_;          // [3584][1024]
    ushort* WprojT = WallT + (size_t)NALL_ * C_;    // [1024][1024]
    ushort* yb16   = WprojT + (size_t)C_ * C_;      // [4096][1024]
    ushort* act    = yb16 + (size_t)M * C_;         // [4096][3584]
    ushort* vt     = act + (size_t)M * NALL_;       // [2*16][64][2048]
    // total ~63 MB

    dim3 blk(256);
    prep<<<dim3(8704), blk, 0, stream>>>(x, x16, Wqk_short, Wv_short, Wqk_long,
                                         Wv_long, Wproj, WallT, WprojT);

    // fused input projections -> act bf16 [4096][3584]
    gemm_bf16<ushort><<<dim3(NALL_ / 128, M / 128), blk, 0, stream>>>(
        x16, WallT, act, M, NALL_, C_);

    // V pre-transpose: act V-cols -> vt[b][gh][d][T]
    vtrans<<<dim3(T_ / 64, 16, B_), blk, 0, stream>>>(act, vt);

    // fused attention (long heads y=0..7, short y=8..15)
    const int attn_lds = (64 * (DL_ + 8) + 64 * 72 * 2) * 2;  // 35840 B
    attn_fused<<<dim3(T_ / 64, 16, B_), blk, attn_lds, stream>>>(act, vt, yb16);

    // output projection (fp32 out)
    gemm_bf16<float><<<dim3(C_ / 128, M / 128), blk, 0, stream>>>(
        yb16, WprojT, out, M, C_, C_);
}